// Round 1
// baseline (157.386 us; speedup 1.0000x reference)
//
#include <hip/hip_runtime.h>
#include <math.h>

// Problem constants (fixed by the reference setup)
#define BATCH      16384
#define CLIP       50
#define DIM        64
#define PAD_IDX    100000

// One wave (64 lanes) per batch element; lane == embedding dim.
__global__ __launch_bounds__(256) void gmf_kernel(
    const int*   __restrict__ user_indices,        // [B]
    const int*   __restrict__ item_indices,        // [B]
    const int*   __restrict__ user_friend_indices, // [NU, CLIP]
    const float* __restrict__ emb_user,            // [PAD_IDX+1, D]
    const float* __restrict__ emb_item,            // [NI, D]
    const float* __restrict__ affine_w,            // [D]
    const float* __restrict__ affine_b,            // [1]
    float*       __restrict__ out)                 // [B] ratings ++ [B*CLIP] gates
{
    const int wave = (blockIdx.x * blockDim.x + threadIdx.x) >> 6;
    const int lane = threadIdx.x & 63;
    if (wave >= BATCH) return;

    const int b  = wave;
    const int u  = user_indices[b];   // wave-uniform
    const int it = item_indices[b];   // wave-uniform

    const float bias = affine_b[0];
    const float ie   = emb_item[(long long)it * DIM + lane]; // coalesced 256B
    const float w    = affine_w[lane];
    const float v    = ie * w;

    const int* fi_row = user_friend_indices + (long long)u * CLIP;

    float acc   = 0.0f;  // sum_c fe[c][lane] * g[c]
    float gkeep = 0.0f;  // lane c keeps g[c] for the coalesced gate store
    int   cnt   = 0;     // number of real friends (wave-uniform)

    #pragma unroll 5
    for (int c = 0; c < CLIP; ++c) {
        const int f = fi_row[c];                 // uniform -> scalar load
        const bool real = (f != PAD_IDX);
        cnt += real ? 1 : 0;

        float fe = emb_user[(long long)f * DIM + lane]; // coalesced 256B gather
        if (!real) fe = 0.0f;                    // padding_idx semantics

        // dot(fe, ie*w) across the wave
        float p = fe * v;
        #pragma unroll
        for (int off = 32; off > 0; off >>= 1)
            p += __shfl_xor(p, off, 64);

        const float g = 1.0f / (1.0f + __expf(-(p + bias)));
        if (lane == c) gkeep = g;
        acc += fe * g;
    }

    // user_emb[lane] = acc / friend_num; logits = dot(user_emb * ie, w) + b
    float q = (acc / (float)cnt) * v;
    #pragma unroll
    for (int off = 32; off > 0; off >>= 1)
        q += __shfl_xor(q, off, 64);

    const float rating = 1.0f / (1.0f + __expf(-(q + bias)));

    if (lane == 0)
        out[b] = rating;
    if (lane < CLIP)
        out[BATCH + (long long)b * CLIP + lane] = gkeep; // coalesced-ish 200B
}

extern "C" void kernel_launch(void* const* d_in, const int* in_sizes, int n_in,
                              void* d_out, int out_size, void* d_ws, size_t ws_size,
                              hipStream_t stream) {
    const int*   user_indices        = (const int*)  d_in[0];
    const int*   item_indices        = (const int*)  d_in[1];
    const int*   user_friend_indices = (const int*)  d_in[2];
    const float* emb_user            = (const float*)d_in[3];
    const float* emb_item            = (const float*)d_in[4];
    const float* affine_w            = (const float*)d_in[5];
    const float* affine_b            = (const float*)d_in[6];
    float*       out                 = (float*)d_out;

    // One wave per batch element: BATCH*64 threads, 256/block.
    const int threads = 256;
    const int blocks  = (BATCH * 64) / threads; // 4096
    gmf_kernel<<<blocks, threads, 0, stream>>>(
        user_indices, item_indices, user_friend_indices,
        emb_user, emb_item, affine_w, affine_b, out);
}

// Round 2
// 128.810 us; speedup vs baseline: 1.2218x; 1.2218x over previous
//
#include <hip/hip_runtime.h>
#include <math.h>

// Problem constants (fixed by the reference setup)
#define BATCH      16384
#define CLIP       50
#define DIM        64
#define PAD_IDX    100000
#define NITER      13   // ceil(CLIP/4) friends processed 4 at a time

// One wave per batch element.
// Lane mapping: sub = lane>>4 (friend within group of 4), li = lane&15
// (dim chunk: each lane owns dims [li*4, li*4+4) as a float4).
__global__ __launch_bounds__(256) void gmf_kernel(
    const int*   __restrict__ user_indices,        // [B]
    const int*   __restrict__ item_indices,        // [B]
    const int*   __restrict__ user_friend_indices, // [NU, CLIP]
    const float* __restrict__ emb_user,            // [PAD_IDX+1, D] (pad row = 0)
    const float* __restrict__ emb_item,            // [NI, D]
    const float* __restrict__ affine_w,            // [D]
    const float* __restrict__ affine_b,            // [1]
    float*       __restrict__ out)                 // [B] ratings ++ [B*CLIP] gates
{
    const int wave = (blockIdx.x * blockDim.x + threadIdx.x) >> 6;
    const int lane = threadIdx.x & 63;
    if (wave >= BATCH) return;

    const int b   = wave;
    const int sub = lane >> 4;   // friend slot in group of 4
    const int li  = lane & 15;   // dim-chunk index

    const int u  = user_indices[b];   // wave-uniform
    const int it = item_indices[b];   // wave-uniform
    const float bias = affine_b[0];

    const float4 ie = *(const float4*)(emb_item + (size_t)it * DIM + li * 4);
    const float4 w4 = *(const float4*)(affine_w + li * 4);
    float4 v;
    v.x = ie.x * w4.x; v.y = ie.y * w4.y; v.z = ie.z * w4.z; v.w = ie.w * w4.w;

    const int* fi_row = user_friend_indices + (size_t)u * CLIP;

    float4 acc = make_float4(0.f, 0.f, 0.f, 0.f);
    float gkeep = 0.f;   // lane (li,sub) keeps gate of friend 4*li+sub
    float cntf  = 0.f;   // partial real-friend count (lanes with li==0)

    #pragma unroll
    for (int i = 0; i < NITER; ++i) {
        const int c = 4 * i + sub;
        const bool valid = (c < CLIP);           // compile-time except i==12
        const int f = valid ? fi_row[c] : PAD_IDX;

        // pad row of emb_user is all-zero -> no mask needed on fe
        const float4 fe = *(const float4*)(emb_user + (size_t)f * DIM + li * 4);

        // partial dot over this lane's 4 dims, then 16-lane butterfly:
        // reduces all 4 friends' dots simultaneously.
        float p = fe.x * v.x + fe.y * v.y + fe.z * v.z + fe.w * v.w;
        p += __shfl_xor(p, 1, 64);
        p += __shfl_xor(p, 2, 64);
        p += __shfl_xor(p, 4, 64);
        p += __shfl_xor(p, 8, 64);

        const float g = 1.0f / (1.0f + __expf(-(p + bias)));

        acc.x += fe.x * g; acc.y += fe.y * g;
        acc.z += fe.z * g; acc.w += fe.w * g;

        if (li == i) gkeep = g;
        cntf += (f != PAD_IDX && li == 0) ? 1.0f : 0.0f;
    }

    // Sum acc over the 4 friend-groups (lanes with equal li): xor 16, 32.
    acc.x += __shfl_xor(acc.x, 16, 64); acc.x += __shfl_xor(acc.x, 32, 64);
    acc.y += __shfl_xor(acc.y, 16, 64); acc.y += __shfl_xor(acc.y, 32, 64);
    acc.z += __shfl_xor(acc.z, 16, 64); acc.z += __shfl_xor(acc.z, 32, 64);
    acc.w += __shfl_xor(acc.w, 16, 64); acc.w += __shfl_xor(acc.w, 32, 64);

    // Friend count: full 6-step butterfly (partials live on li==0 lanes).
    cntf += __shfl_xor(cntf, 1, 64);
    cntf += __shfl_xor(cntf, 2, 64);
    cntf += __shfl_xor(cntf, 4, 64);
    cntf += __shfl_xor(cntf, 8, 64);
    cntf += __shfl_xor(cntf, 16, 64);
    cntf += __shfl_xor(cntf, 32, 64);

    // logits = sum_d (acc[d]/cnt) * ie[d] * w[d]
    float q = (acc.x * v.x + acc.y * v.y + acc.z * v.z + acc.w * v.w) / cntf;
    q += __shfl_xor(q, 1, 64);
    q += __shfl_xor(q, 2, 64);
    q += __shfl_xor(q, 4, 64);
    q += __shfl_xor(q, 8, 64);

    const float rating = 1.0f / (1.0f + __expf(-(q + bias)));

    if (lane == 0)
        out[b] = rating;

    // Gate store: lane (li,sub) holds gate of friend c = 4*li+sub.
    const int c = 4 * li + sub;
    if (c < CLIP)
        out[BATCH + (size_t)b * CLIP + c] = gkeep;  // one 200B scattered store
}

extern "C" void kernel_launch(void* const* d_in, const int* in_sizes, int n_in,
                              void* d_out, int out_size, void* d_ws, size_t ws_size,
                              hipStream_t stream) {
    const int*   user_indices        = (const int*)  d_in[0];
    const int*   item_indices        = (const int*)  d_in[1];
    const int*   user_friend_indices = (const int*)  d_in[2];
    const float* emb_user            = (const float*)d_in[3];
    const float* emb_item            = (const float*)d_in[4];
    const float* affine_w            = (const float*)d_in[5];
    const float* affine_b            = (const float*)d_in[6];
    float*       out                 = (float*)d_out;

    const int threads = 256;
    const int blocks  = (BATCH * 64) / threads; // 4096
    gmf_kernel<<<blocks, threads, 0, stream>>>(
        user_indices, item_indices, user_friend_indices,
        emb_user, emb_item, affine_w, affine_b, out);
}

// Round 3
// 127.528 us; speedup vs baseline: 1.2341x; 1.0101x over previous
//
#include <hip/hip_runtime.h>
#include <math.h>

// Problem constants (fixed by the reference setup)
#define BATCH      16384
#define CLIP       50
#define DIM        64
#define PAD_IDX    100000
#define NITER      13   // ceil(CLIP/4) friends processed 4 at a time

// One wave per batch element.
// Lane mapping: sub = lane>>4 (friend slot within group of 4), li = lane&15
// (dim chunk: each lane owns dims [li*4, li*4+4) as a float4).
//
// Structure: (1) load all friend ids, (2) issue ALL 13 float4 gathers
// back-to-back (max memory-level parallelism), (3) reduce/sigmoid chain.
__global__ __launch_bounds__(256) void gmf_kernel(
    const int*   __restrict__ user_indices,        // [B]
    const int*   __restrict__ item_indices,        // [B]
    const int*   __restrict__ user_friend_indices, // [NU, CLIP]
    const float* __restrict__ emb_user,            // [PAD_IDX+1, D] (pad row = 0)
    const float* __restrict__ emb_item,            // [NI, D]
    const float* __restrict__ affine_w,            // [D]
    const float* __restrict__ affine_b,            // [1]
    float*       __restrict__ out)                 // [B] ratings ++ [B*CLIP] gates
{
    const int wave = (blockIdx.x * blockDim.x + threadIdx.x) >> 6;
    const int lane = threadIdx.x & 63;
    if (wave >= BATCH) return;

    const int b   = wave;
    const int sub = lane >> 4;   // friend slot in group of 4
    const int li  = lane & 15;   // dim-chunk index

    const int u  = user_indices[b];   // wave-uniform
    const int it = item_indices[b];   // wave-uniform
    const float bias = affine_b[0];

    const float4 ie = *(const float4*)(emb_item + (size_t)it * DIM + li * 4);
    const float4 w4 = *(const float4*)(affine_w + li * 4);
    float4 v;
    v.x = ie.x * w4.x; v.y = ie.y * w4.y; v.z = ie.z * w4.z; v.w = ie.w * w4.w;

    const int* fi_row = user_friend_indices + (size_t)u * CLIP;

    // Phase 1: friend ids for this lane's 13 slots (c = 4*i + sub).
    int fidx[NITER];
    #pragma unroll
    for (int i = 0; i < NITER; ++i) {
        const int c = 4 * i + sub;
        fidx[i] = (c < CLIP) ? fi_row[c] : PAD_IDX;
    }

    // Phase 2: issue all 13 gathers (pad row of emb_user is all-zero).
    float4 fe[NITER];
    #pragma unroll
    for (int i = 0; i < NITER; ++i)
        fe[i] = *(const float4*)(emb_user + (size_t)fidx[i] * DIM + li * 4);

    // Phase 3: per-friend gate + gated accumulation.
    float4 acc = make_float4(0.f, 0.f, 0.f, 0.f);
    float gkeep = 0.f;   // lane (li,sub) keeps gate of friend 4*li+sub
    float cl    = 0.f;   // per-lane real-friend count over its 13 slots

    #pragma unroll
    for (int i = 0; i < NITER; ++i) {
        // partial dot over this lane's 4 dims, then 16-lane butterfly
        // (reduces all 4 friends-in-flight simultaneously).
        float p = fe[i].x * v.x + fe[i].y * v.y + fe[i].z * v.z + fe[i].w * v.w;
        p += __shfl_xor(p, 1, 64);
        p += __shfl_xor(p, 2, 64);
        p += __shfl_xor(p, 4, 64);
        p += __shfl_xor(p, 8, 64);

        const float g = 1.0f / (1.0f + __expf(-(p + bias)));

        acc.x += fe[i].x * g; acc.y += fe[i].y * g;
        acc.z += fe[i].z * g; acc.w += fe[i].w * g;

        if (li == i) gkeep = g;
        cl += (fidx[i] != PAD_IDX) ? 1.0f : 0.0f;  // c>=CLIP slots hold PAD_IDX
    }

    // Friend count: lanes sharing `sub` are identical copies; sum the 4 groups.
    float cntf = cl;
    cntf += __shfl_xor(cntf, 16, 64);
    cntf += __shfl_xor(cntf, 32, 64);

    // logits: full-wave reduce of acc·v (covers both dim and friend-group sums).
    float q = acc.x * v.x + acc.y * v.y + acc.z * v.z + acc.w * v.w;
    q += __shfl_xor(q, 1, 64);
    q += __shfl_xor(q, 2, 64);
    q += __shfl_xor(q, 4, 64);
    q += __shfl_xor(q, 8, 64);
    q += __shfl_xor(q, 16, 64);
    q += __shfl_xor(q, 32, 64);

    const float rating = 1.0f / (1.0f + __expf(-(q / cntf + bias)));

    if (lane == 0)
        out[b] = rating;

    // Gate store: lane (li,sub) holds gate of friend c = 4*li+sub.
    const int c = 4 * li + sub;
    if (c < CLIP)
        out[BATCH + (size_t)b * CLIP + c] = gkeep;  // one 200B scattered store
}

extern "C" void kernel_launch(void* const* d_in, const int* in_sizes, int n_in,
                              void* d_out, int out_size, void* d_ws, size_t ws_size,
                              hipStream_t stream) {
    const int*   user_indices        = (const int*)  d_in[0];
    const int*   item_indices        = (const int*)  d_in[1];
    const int*   user_friend_indices = (const int*)  d_in[2];
    const float* emb_user            = (const float*)d_in[3];
    const float* emb_item            = (const float*)d_in[4];
    const float* affine_w            = (const float*)d_in[5];
    const float* affine_b            = (const float*)d_in[6];
    float*       out                 = (float*)d_out;

    const int threads = 256;
    const int blocks  = (BATCH * 64) / threads; // 4096
    gmf_kernel<<<blocks, threads, 0, stream>>>(
        user_indices, item_indices, user_friend_indices,
        emb_user, emb_item, affine_w, affine_b, out);
}